// Round 8
// baseline (365.343 us; speedup 1.0000x reference)
//
#include <hip/hip_runtime.h>
#include <math.h>

typedef __bf16 bf16x8 __attribute__((ext_vector_type(8)));
typedef float f32x4 __attribute__((ext_vector_type(4)));
typedef unsigned short ushort_t;

#define SEQ 2048
#define MROWS 4096          // B*S
#define EPS 1e-5f
#define QKS 3200            // fused qkv output row stride (q 0..1023, k 1024.., v 2048.., gate 3072..3087, pad)

// ---------- bf16 helpers (manual bit ops — the r4-proven idiom set) ----------
__device__ __forceinline__ float bf2f(ushort_t u) {
  union { unsigned int i; float f; } c; c.i = ((unsigned int)u) << 16; return c.f;
}
__device__ __forceinline__ ushort_t f2bf(float f) {
  union { unsigned int i; float f; } c; c.f = f;
  unsigned int i = c.i;
  unsigned int r = i + 0x7fffu + ((i >> 16) & 1u);   // RNE
  return (ushort_t)(r >> 16);
}

// ---------- reductions ----------
__device__ __forceinline__ float wave_sum(float v) {
  #pragma unroll
  for (int off = 32; off > 0; off >>= 1) v += __shfl_xor(v, off);
  return v;
}

// ---------- 0a. dtype detector: is x bf16 (1) or fp32 (0)? ----------
__global__ void detect_kernel(const unsigned int* __restrict__ xraw, int* __restrict__ flag) {
  int tid = threadIdx.x;
  int cnt = 0;
  for (int i = tid; i < 4096; i += 256) {
    unsigned int e = (xraw[i] >> 7) & 0xFFu;
    cnt += (e >= 100u && e <= 150u) ? 1 : 0;
  }
  __shared__ int sred[256];
  sred[tid] = cnt;
  __syncthreads();
  for (int s = 128; s > 0; s >>= 1) {
    if (tid < s) sred[tid] += sred[tid + s];
    __syncthreads();
  }
  if (tid == 0) flag[0] = (sred[0] > 2048) ? 1 : 0;
}

// ---------- 0b. canonicalize ----------
__global__ void conv_f32(const void* __restrict__ in, float* __restrict__ outp,
                         int n, const int* __restrict__ flag) {
  int i = blockIdx.x * 256 + threadIdx.x;
  if (i >= n) return;
  if (*flag) outp[i] = bf2f(((const ushort_t*)in)[i]);
  else       outp[i] = ((const float*)in)[i];
}
__global__ void conv_b16(const void* __restrict__ in, ushort_t* __restrict__ outp,
                         int n, const int* __restrict__ flag) {
  int i = blockIdx.x * 256 + threadIdx.x;
  if (i >= n) return;
  if (*flag) outp[i] = ((const ushort_t*)in)[i];
  else       outp[i] = f2bf(((const float*)in)[i]);
}

// ---------- 1. prenorm RMSNorm (raw x per flag -> bf16 xn) ----------
__global__ void prenorm_kernel(const void* __restrict__ xraw,
                               const float* __restrict__ w,
                               ushort_t* __restrict__ xn,
                               const int* __restrict__ flag) {
  int row = blockIdx.x;
  int tid = threadIdx.x;
  float4 u;
  if (*flag) {
    ushort4 s = ((const ushort4*)xraw)[row * 256 + tid];
    u.x = bf2f(s.x); u.y = bf2f(s.y); u.z = bf2f(s.z); u.w = bf2f(s.w);
  } else {
    u = ((const float4*)xraw)[row * 256 + tid];
  }
  float ss = u.x*u.x + u.y*u.y + u.z*u.z + u.w*u.w;
  ss = wave_sum(ss);
  __shared__ float red[4];
  if ((tid & 63) == 0) red[tid >> 6] = ss;
  __syncthreads();
  float total = red[0] + red[1] + red[2] + red[3];
  float inv = rsqrtf(total * (1.0f / 1024.0f) + EPS);
  float4 wu = ((const float4*)w)[tid];
  ushort4 o;
  o.x = f2bf(u.x * inv * wu.x);
  o.y = f2bf(u.y * inv * wu.y);
  o.z = f2bf(u.z * inv * wu.z);
  o.w = f2bf(u.w * inv * wu.w);
  ((ushort4*)(xn + (long long)row * 1024))[tid] = o;
}

// ---------- async global->LDS 16B ----------
__device__ __forceinline__ void gll16(const ushort_t* g, ushort_t* l) {
  __builtin_amdgcn_global_load_lds(
      (const __attribute__((address_space(1))) unsigned int*)g,
      (__attribute__((address_space(3))) unsigned int*)l, 16, 0, 0);
}

// ---------- 2. fused qkv+gate GEMM, 128x128 tile (m97 structure) ----------
__global__ void gemm_qkv_fused(const ushort_t* __restrict__ A, const ushort_t* __restrict__ B,
                               ushort_t* __restrict__ C, float* __restrict__ gate,
                               const float* __restrict__ qw, const float* __restrict__ kw) {
  __shared__ ushort_t As[128 * 32];
  __shared__ ushort_t Bs[128 * 32];
  int tid = threadIdx.x, wave = tid >> 6, lane = tid & 63;
  int m_blk = blockIdx.y * 128, n_blk = blockIdx.x * 128;
  int wm = (wave & 1) * 64, wn = (wave >> 1) * 64;
  int g = lane >> 4, c = lane & 15;
  int arow = lane >> 2;
  int akc = (lane & 3) << 3;
  f32x4 acc[4][4] = {};
  for (int kt = 0; kt < 1024; kt += 32) {
    #pragma unroll
    for (int i = 0; i < 2; ++i) {
      int rbase = (i * 4 + wave) * 16;
      gll16(A + (long long)(m_blk + rbase + arow) * 1024 + kt + akc, &As[rbase * 32]);
      gll16(B + (long long)(n_blk + rbase + arow) * 1024 + kt + akc, &Bs[rbase * 32]);
    }
    __syncthreads();
    bf16x8 af[4], bfr[4];
    #pragma unroll
    for (int mi = 0; mi < 4; ++mi)
      af[mi] = *(const bf16x8*)&As[(wm + mi * 16 + c) * 32 + (g << 3)];
    #pragma unroll
    for (int ni = 0; ni < 4; ++ni)
      bfr[ni] = *(const bf16x8*)&Bs[(wn + ni * 16 + c) * 32 + (g << 3)];
    #pragma unroll
    for (int mi = 0; mi < 4; ++mi)
      #pragma unroll
      for (int ni = 0; ni < 4; ++ni)
        acc[mi][ni] = __builtin_amdgcn_mfma_f32_16x16x32_bf16(af[mi], bfr[ni], acc[mi][ni], 0, 0, 0);
    __syncthreads();
  }
  int col_base = n_blk + wn;   // 64-aligned; never straddles q/k/v/gate boundaries
  if (col_base < 2048) {
    int isk = col_base >= 1024;
    float scale = isk ? 1.0f : 0.125f;       // 1/sqrt(HEAD_DIM) folded into q
    const float* nw = isk ? kw : qw;
    float w[4];
    #pragma unroll
    for (int ni = 0; ni < 4; ++ni) w[ni] = nw[ni * 16 + c];
    #pragma unroll
    for (int mi = 0; mi < 4; ++mi)
      #pragma unroll
      for (int r = 0; r < 4; ++r) {
        float ss = 0.f;
        #pragma unroll
        for (int ni = 0; ni < 4; ++ni) ss += acc[mi][ni][r] * acc[mi][ni][r];
        #pragma unroll
        for (int off = 8; off > 0; off >>= 1) ss += __shfl_xor(ss, off);
        float inv = rsqrtf(ss * (1.0f / 64.0f) + EPS) * scale;
        int row = m_blk + wm + mi * 16 + g * 4 + r;
        #pragma unroll
        for (int ni = 0; ni < 4; ++ni)
          C[(long long)row * QKS + col_base + ni * 16 + c] = f2bf(acc[mi][ni][r] * inv * w[ni]);
      }
  } else if (col_base < 3072) {
    #pragma unroll
    for (int mi = 0; mi < 4; ++mi)
      #pragma unroll
      for (int r = 0; r < 4; ++r) {
        int row = m_blk + wm + mi * 16 + g * 4 + r;
        #pragma unroll
        for (int ni = 0; ni < 4; ++ni)
          C[(long long)row * QKS + col_base + ni * 16 + c] = f2bf(acc[mi][ni][r]);
      }
  } else if (col_base == 3072) {
    #pragma unroll
    for (int mi = 0; mi < 4; ++mi)
      #pragma unroll
      for (int r = 0; r < 4; ++r) {
        int row = m_blk + wm + mi * 16 + g * 4 + r;
        float v = acc[mi][0][r];
        gate[(long long)row * 16 + c] = 1.0f / (1.0f + __expf(-v));
      }
  }
}

// ---------- 3. generic tiled GEMM (o-proj): C=A@B^T (+res), dtype-dispatched ----------
__global__ void gemm_tiled(const ushort_t* __restrict__ A, const ushort_t* __restrict__ B,
                           void* __restrict__ Cv, const void* __restrict__ res,
                           const int* __restrict__ flag,
                           int K, int lda, int ldb, int ldc) {
  __shared__ ushort_t As[128 * 32];
  __shared__ ushort_t Bs[128 * 32];
  int tid = threadIdx.x, wave = tid >> 6, lane = tid & 63;
  int m_blk = blockIdx.y * 128, n_blk = blockIdx.x * 128;
  int wm = (wave & 1) * 64, wn = (wave >> 1) * 64;
  int g = lane >> 4, c = lane & 15;
  int arow = lane >> 2;
  int akc = (lane & 3) << 3;
  f32x4 acc[4][4] = {};
  for (int kt = 0; kt < K; kt += 32) {
    #pragma unroll
    for (int i = 0; i < 2; ++i) {
      int rbase = (i * 4 + wave) * 16;
      gll16(A + (long long)(m_blk + rbase + arow) * lda + kt + akc, &As[rbase * 32]);
      gll16(B + (long long)(n_blk + rbase + arow) * ldb + kt + akc, &Bs[rbase * 32]);
    }
    __syncthreads();
    bf16x8 af[4], bfr[4];
    #pragma unroll
    for (int mi = 0; mi < 4; ++mi)
      af[mi] = *(const bf16x8*)&As[(wm + mi * 16 + c) * 32 + (g << 3)];
    #pragma unroll
    for (int ni = 0; ni < 4; ++ni)
      bfr[ni] = *(const bf16x8*)&Bs[(wn + ni * 16 + c) * 32 + (g << 3)];
    #pragma unroll
    for (int mi = 0; mi < 4; ++mi)
      #pragma unroll
      for (int ni = 0; ni < 4; ++ni)
        acc[mi][ni] = __builtin_amdgcn_mfma_f32_16x16x32_bf16(af[mi], bfr[ni], acc[mi][ni], 0, 0, 0);
    __syncthreads();
  }
  int outbf = flag ? *flag : 1;
  #pragma unroll
  for (int mi = 0; mi < 4; ++mi)
    #pragma unroll
    for (int ni = 0; ni < 4; ++ni)
      #pragma unroll
      for (int r = 0; r < 4; ++r) {
        int row = m_blk + wm + mi * 16 + g * 4 + r;
        int col = n_blk + wn + ni * 16 + c;
        long long idx = (long long)row * ldc + col;
        float v = acc[mi][ni][r];
        if (res) v += outbf ? bf2f(((const ushort_t*)res)[idx]) : ((const float*)res)[idx];
        if (outbf) ((ushort_t*)Cv)[idx] = f2bf(v);
        else       ((float*)Cv)[idx] = v;
      }
}

// ---------- 4. V transpose (bf16): Vt[bh][d][s] = qkv2[b*S+s][2048+h*64+d] ----------
__global__ void vt_kernel(const ushort_t* __restrict__ qkv, ushort_t* __restrict__ Vt) {
  __shared__ ushort_t tile[64][65];
  int s0 = blockIdx.x * 64;
  int bh = blockIdx.y;
  int b = bh >> 4, h = bh & 15;
  const ushort_t* src = qkv + (long long)b * SEQ * QKS + 2048 + h * 64;
  int d = threadIdx.x & 63, srow = threadIdx.x >> 6;
  #pragma unroll
  for (int i = 0; i < 16; ++i) {
    int sl = i * 4 + srow;
    tile[sl][d] = src[(long long)(s0 + sl) * QKS + d];
  }
  __syncthreads();
  ushort_t* dst = Vt + (long long)bh * 64 * SEQ + s0;
  int sl2 = threadIdx.x & 63, drow = threadIdx.x >> 6;
  #pragma unroll
  for (int i = 0; i < 16; ++i) {
    int dd = i * 4 + drow;
    dst[(long long)dd * SEQ + sl2] = tile[sl2][dd];
  }
}

// ---------- 5. flash attention: r4 structure + XOR chunk swizzle (all strides 64) ----------
// grid (SEQ/64, 32). C-layout S, per-row online softmax (xor<=8 only), P via per-wave
// LDS. 16B chunk ch of LDS row r lives at ch^(r&7): staging writes and fragment
// reads both spread 8 lanes per 4-bank group -> conflict-free (r7-verified).
__global__ void flash_kernel(const ushort_t* __restrict__ qkv, const ushort_t* __restrict__ Vt,
                             const float* __restrict__ gate, ushort_t* __restrict__ ao) {
  __shared__ ushort_t Ks[64 * 64];
  __shared__ ushort_t Vs[64 * 64];
  __shared__ ushort_t Ps[4][16 * 64];
  int tid = threadIdx.x, wave = tid >> 6, lane = tid & 63;
  int g = lane >> 4, c = lane & 15;
  int q0 = blockIdx.x * 64;
  int bh = blockIdx.y, b = bh >> 4, h = bh & 15;
  const ushort_t* qbase = qkv + (long long)b * SEQ * QKS + h * 64;
  const ushort_t* kbase = qbase + 1024;
  const ushort_t* vtbase = Vt + (long long)bh * 64 * SEQ;
  // q A-fragment: m=c, k=8g+j (and +32)
  int qrow = q0 + wave * 16 + c;
  bf16x8 qa0 = *(const bf16x8*)(qbase + (long long)qrow * QKS + (g << 3));
  bf16x8 qa1 = *(const bf16x8*)(qbase + (long long)qrow * QKS + 32 + (g << 3));
  f32x4 accO[4] = {};
  float m_i[4] = {-1e30f, -1e30f, -1e30f, -1e30f};
  float l_i[4] = {0.f, 0.f, 0.f, 0.f};
  int srow = tid >> 3;            // 0..31 (two t-iters: +32)
  int schk = tid & 7;             // 16B chunk index 0..7
  uint4 pk[2], pv[2];
  #pragma unroll
  for (int t = 0; t < 2; ++t) {
    int row = t * 32 + srow;
    pk[t] = *(const uint4*)(kbase + (long long)row * QKS + (schk << 3));
    pv[t] = *(const uint4*)(vtbase + (long long)row * SEQ + (schk << 3));
  }
  for (int s0 = 0; s0 < SEQ; s0 += 64) {
    #pragma unroll
    for (int t = 0; t < 2; ++t) {
      int row = t * 32 + srow;
      int sc = (schk ^ (row & 7)) << 3;     // swizzled chunk
      *(uint4*)&Ks[row * 64 + sc] = pk[t];
      *(uint4*)&Vs[row * 64 + sc] = pv[t];
    }
    if (s0 + 64 < SEQ) {
      #pragma unroll
      for (int t = 0; t < 2; ++t) {
        int row = t * 32 + srow;
        pk[t] = *(const uint4*)(kbase + (long long)(s0 + 64 + row) * QKS + (schk << 3));
        pv[t] = *(const uint4*)(vtbase + (long long)row * SEQ + s0 + 64 + (schk << 3));
      }
    }
    __syncthreads();
    // S = q.k^T (C-layout): sacc[ni][r] = S[q=4g+r][s=16ni+c]
    f32x4 sacc[4] = {};
    #pragma unroll
    for (int ni = 0; ni < 4; ++ni) {
      int n = ni * 16 + c;
      bf16x8 kb0 = *(const bf16x8*)&Ks[n * 64 + ((g ^ (n & 7)) << 3)];
      bf16x8 kb1 = *(const bf16x8*)&Ks[n * 64 + (((4 + g) ^ (n & 7)) << 3)];
      sacc[ni] = __builtin_amdgcn_mfma_f32_16x16x32_bf16(qa0, kb0, sacc[ni], 0, 0, 0);
      sacc[ni] = __builtin_amdgcn_mfma_f32_16x16x32_bf16(qa1, kb1, sacc[ni], 0, 0, 0);
    }
    // per-row online softmax; 16-lane reduce (xor 8,4,2,1 stays in the g-group)
    float alpha[4];
    #pragma unroll
    for (int r = 0; r < 4; ++r) {
      float mx = fmaxf(fmaxf(sacc[0][r], sacc[1][r]), fmaxf(sacc[2][r], sacc[3][r]));
      #pragma unroll
      for (int off = 8; off > 0; off >>= 1) mx = fmaxf(mx, __shfl_xor(mx, off));
      float mn = fmaxf(m_i[r], mx);
      alpha[r] = __expf(m_i[r] - mn);
      m_i[r] = mn;
      int q = g * 4 + r;
      int sw = (q & 7) << 3;                // row swizzle mask (elements)
      float rs = 0.f;
      #pragma unroll
      for (int ni = 0; ni < 4; ++ni) {
        float p = __expf(sacc[ni][r] - mn);
        rs += p;
        int col = ni * 16 + c;
        Ps[wave][q * 64 + ((col & 56) ^ sw) + (col & 7)] = f2bf(p);
      }
      #pragma unroll
      for (int off = 8; off > 0; off >>= 1) rs += __shfl_xor(rs, off);
      l_i[r] = l_i[r] * alpha[r] + rs;
    }
    #pragma unroll
    for (int di = 0; di < 4; ++di)
      #pragma unroll
      for (int r = 0; r < 4; ++r) accO[di][r] *= alpha[r];
    // P A-fragment: row q=c, chunks g / 4+g (swizzled by c&7)
    bf16x8 pa0 = *(const bf16x8*)&Ps[wave][c * 64 + ((g ^ (c & 7)) << 3)];
    bf16x8 pa1 = *(const bf16x8*)&Ps[wave][c * 64 + (((4 + g) ^ (c & 7)) << 3)];
    // O += P.V : accO[di][r] = O[q=4g+r][d=16di+c]
    #pragma unroll
    for (int di = 0; di < 4; ++di) {
      int n = di * 16 + c;
      bf16x8 vb0 = *(const bf16x8*)&Vs[n * 64 + ((g ^ (n & 7)) << 3)];
      bf16x8 vb1 = *(const bf16x8*)&Vs[n * 64 + (((4 + g) ^ (n & 7)) << 3)];
      accO[di] = __builtin_amdgcn_mfma_f32_16x16x32_bf16(pa0, vb0, accO[di], 0, 0, 0);
      accO[di] = __builtin_amdgcn_mfma_f32_16x16x32_bf16(pa1, vb1, accO[di], 0, 0, 0);
    }
    __syncthreads();
  }
  // epilogue: O * sigmoid(gate) / l -> ao[b][q][h*64+d]
  #pragma unroll
  for (int r = 0; r < 4; ++r) {
    int row = q0 + wave * 16 + g * 4 + r;
    float sg = gate[(long long)(b * SEQ + row) * 16 + h];  // pre-sigmoided
    float scale = sg / l_i[r];
    #pragma unroll
    for (int di = 0; di < 4; ++di) {
      int col = h * 64 + di * 16 + c;
      ao[(long long)(b * SEQ + row) * 1024 + col] = f2bf(accO[di][r] * scale);
    }
  }
}

extern "C" void kernel_launch(void* const* d_in, const int* in_sizes, int n_in,
                              void* d_out, int out_size, void* d_ws, size_t ws_size,
                              hipStream_t stream) {
  (void)in_sizes; (void)n_in; (void)out_size; (void)ws_size;
  char* ws = (char*)d_ws;
  ushort_t* Wcat = (ushort_t*)(ws);                             // 7 MB: 3200x1024 bf16 (qkvw|gw|pad)
  ushort_t* ow   = (ushort_t*)(ws + (7ll << 20));               // 2 MB bf16 1024x1024
  float*    pwf  = (float*)   (ws + (9ll << 20));               // 4 KB
  float*    qnf  = (float*)   (ws + (9ll << 20) + (8 << 10));
  float*    knf  = (float*)   (ws + (9ll << 20) + (12 << 10));
  int*      flag = (int*)     (ws + (9ll << 20) + (16 << 10));
  float*    gate = (float*)   (ws + (9ll << 20) + (64 << 10));  // 256 KB fp32 (sigmoided)
  ushort_t* xn   = (ushort_t*)(ws + (10ll << 20));              // 8 MB bf16 4096x1024
  ushort_t* qkv2 = (ushort_t*)(ws + (18ll << 20));              // 26 MB bf16 4096x3200
  ushort_t* Vt   = (ushort_t*)(ws + (44ll << 20));              // 8 MB bf16 32x64x2048
  ushort_t* ao   = (ushort_t*)(ws + (52ll << 20));              // 8 MB bf16 4096x1024

  // 0. detect + canonicalize weights
  detect_kernel<<<1, 256, 0, stream>>>((const unsigned int*)d_in[0], flag);
  conv_f32<<<4, 256, 0, stream>>>(d_in[1], pwf, 1024, flag);
  conv_b16<<<12288, 256, 0, stream>>>(d_in[2], Wcat, 3145728, flag);          // qkv_w -> rows 0..3071
  conv_b16<<<64, 256, 0, stream>>>(d_in[3], Wcat + 3072 * 1024, 16384, flag); // gate_w -> rows 3072..3087
  conv_b16<<<4096, 256, 0, stream>>>(d_in[4], ow, 1048576, flag);
  conv_f32<<<1, 256, 0, stream>>>(d_in[5], qnf, 64, flag);
  conv_f32<<<1, 256, 0, stream>>>(d_in[6], knf, 64, flag);

  // 1. prenorm (raw x -> bf16 xn)
  prenorm_kernel<<<MROWS, 256, 0, stream>>>(d_in[0], pwf, xn, flag);
  // 2. fused qkv+gate GEMM with qk-norm / sigmoid epilogue (N=3200 incl. pad tile)
  gemm_qkv_fused<<<dim3(25, 32), 256, 0, stream>>>(xn, Wcat, qkv2, gate, qnf, knf);
  // 3. V transpose
  vt_kernel<<<dim3(32, 32), 256, 0, stream>>>(qkv2, Vt);
  // 4. flash attention (fused gate multiply)
  flash_kernel<<<dim3(32, 32), 256, 0, stream>>>(qkv2, Vt, gate, ao);
  // 5. out = ao @ o_w^T + x (raw residual), dtype-dispatched store
  gemm_tiled<<<dim3(8, 32), 256, 0, stream>>>(ao, ow, d_out, d_in[0], flag,
                                              1024, 1024, 1024, 1024);
}

// Round 9
// 296.849 us; speedup vs baseline: 1.2307x; 1.2307x over previous
//
#include <hip/hip_runtime.h>
#include <math.h>

typedef __bf16 bf16x8 __attribute__((ext_vector_type(8)));
typedef float f32x4 __attribute__((ext_vector_type(4)));
typedef unsigned short ushort_t;

#define SEQ 2048
#define MROWS 4096          // B*S
#define EPS 1e-5f
#define QKS 3200            // fused qkv output row stride (q 0..1023, k 1024.., v 2048.., gate 3072..3087, pad)

// ---------- bf16 helpers (manual bit ops — exact-LDS-proven idiom set) ----------
__device__ __forceinline__ float bf2f(ushort_t u) {
  union { unsigned int i; float f; } c; c.i = ((unsigned int)u) << 16; return c.f;
}
__device__ __forceinline__ ushort_t f2bf(float f) {
  union { unsigned int i; float f; } c; c.f = f;
  unsigned int i = c.i;
  unsigned int r = i + 0x7fffu + ((i >> 16) & 1u);   // RNE
  return (ushort_t)(r >> 16);
}

// ---------- reductions ----------
__device__ __forceinline__ float wave_sum(float v) {
  #pragma unroll
  for (int off = 32; off > 0; off >>= 1) v += __shfl_xor(v, off);
  return v;
}

// ---------- 0a. dtype detector: is x bf16 (1) or fp32 (0)? ----------
__global__ void detect_kernel(const unsigned int* __restrict__ xraw, int* __restrict__ flag) {
  int tid = threadIdx.x;
  int cnt = 0;
  for (int i = tid; i < 4096; i += 256) {
    unsigned int e = (xraw[i] >> 7) & 0xFFu;
    cnt += (e >= 100u && e <= 150u) ? 1 : 0;
  }
  __shared__ int sred[256];
  sred[tid] = cnt;
  __syncthreads();
  for (int s = 128; s > 0; s >>= 1) {
    if (tid < s) sred[tid] += sred[tid + s];
    __syncthreads();
  }
  if (tid == 0) flag[0] = (sred[0] > 2048) ? 1 : 0;
}

// ---------- 0b. canonicalize ----------
__global__ void conv_f32(const void* __restrict__ in, float* __restrict__ outp,
                         int n, const int* __restrict__ flag) {
  int i = blockIdx.x * 256 + threadIdx.x;
  if (i >= n) return;
  if (*flag) outp[i] = bf2f(((const ushort_t*)in)[i]);
  else       outp[i] = ((const float*)in)[i];
}
__global__ void conv_b16(const void* __restrict__ in, ushort_t* __restrict__ outp,
                         int n, const int* __restrict__ flag) {
  int i = blockIdx.x * 256 + threadIdx.x;
  if (i >= n) return;
  if (*flag) outp[i] = ((const ushort_t*)in)[i];
  else       outp[i] = f2bf(((const float*)in)[i]);
}

// ---------- 1. prenorm RMSNorm (raw x per flag -> bf16 xn) ----------
__global__ void prenorm_kernel(const void* __restrict__ xraw,
                               const float* __restrict__ w,
                               ushort_t* __restrict__ xn,
                               const int* __restrict__ flag) {
  int row = blockIdx.x;
  int tid = threadIdx.x;
  float4 u;
  if (*flag) {
    ushort4 s = ((const ushort4*)xraw)[row * 256 + tid];
    u.x = bf2f(s.x); u.y = bf2f(s.y); u.z = bf2f(s.z); u.w = bf2f(s.w);
  } else {
    u = ((const float4*)xraw)[row * 256 + tid];
  }
  float ss = u.x*u.x + u.y*u.y + u.z*u.z + u.w*u.w;
  ss = wave_sum(ss);
  __shared__ float red[4];
  if ((tid & 63) == 0) red[tid >> 6] = ss;
  __syncthreads();
  float total = red[0] + red[1] + red[2] + red[3];
  float inv = rsqrtf(total * (1.0f / 1024.0f) + EPS);
  float4 wu = ((const float4*)w)[tid];
  ushort4 o;
  o.x = f2bf(u.x * inv * wu.x);
  o.y = f2bf(u.y * inv * wu.y);
  o.z = f2bf(u.z * inv * wu.z);
  o.w = f2bf(u.w * inv * wu.w);
  ((ushort4*)(xn + (long long)row * 1024))[tid] = o;
}

// ---------- async global->LDS 16B ----------
__device__ __forceinline__ void gll16(const ushort_t* g, ushort_t* l) {
  __builtin_amdgcn_global_load_lds(
      (const __attribute__((address_space(1))) unsigned int*)g,
      (__attribute__((address_space(3))) unsigned int*)l, 16, 0, 0);
}

// ---------- 2. fused qkv+gate GEMM, 128x128 tile (m97 structure) ----------
__global__ void gemm_qkv_fused(const ushort_t* __restrict__ A, const ushort_t* __restrict__ B,
                               ushort_t* __restrict__ C, float* __restrict__ gate,
                               const float* __restrict__ qw, const float* __restrict__ kw) {
  __shared__ ushort_t As[128 * 32];
  __shared__ ushort_t Bs[128 * 32];
  int tid = threadIdx.x, wave = tid >> 6, lane = tid & 63;
  int m_blk = blockIdx.y * 128, n_blk = blockIdx.x * 128;
  int wm = (wave & 1) * 64, wn = (wave >> 1) * 64;
  int g = lane >> 4, c = lane & 15;
  int arow = lane >> 2;
  int akc = (lane & 3) << 3;
  f32x4 acc[4][4] = {};
  for (int kt = 0; kt < 1024; kt += 32) {
    #pragma unroll
    for (int i = 0; i < 2; ++i) {
      int rbase = (i * 4 + wave) * 16;
      gll16(A + (long long)(m_blk + rbase + arow) * 1024 + kt + akc, &As[rbase * 32]);
      gll16(B + (long long)(n_blk + rbase + arow) * 1024 + kt + akc, &Bs[rbase * 32]);
    }
    __syncthreads();
    bf16x8 af[4], bfr[4];
    #pragma unroll
    for (int mi = 0; mi < 4; ++mi)
      af[mi] = *(const bf16x8*)&As[(wm + mi * 16 + c) * 32 + (g << 3)];
    #pragma unroll
    for (int ni = 0; ni < 4; ++ni)
      bfr[ni] = *(const bf16x8*)&Bs[(wn + ni * 16 + c) * 32 + (g << 3)];
    #pragma unroll
    for (int mi = 0; mi < 4; ++mi)
      #pragma unroll
      for (int ni = 0; ni < 4; ++ni)
        acc[mi][ni] = __builtin_amdgcn_mfma_f32_16x16x32_bf16(af[mi], bfr[ni], acc[mi][ni], 0, 0, 0);
    __syncthreads();
  }
  int col_base = n_blk + wn;   // 64-aligned; never straddles q/k/v/gate boundaries
  if (col_base < 2048) {
    int isk = col_base >= 1024;
    float scale = isk ? 1.0f : 0.125f;       // 1/sqrt(HEAD_DIM) folded into q
    const float* nw = isk ? kw : qw;
    float w[4];
    #pragma unroll
    for (int ni = 0; ni < 4; ++ni) w[ni] = nw[ni * 16 + c];
    #pragma unroll
    for (int mi = 0; mi < 4; ++mi)
      #pragma unroll
      for (int r = 0; r < 4; ++r) {
        float ss = 0.f;
        #pragma unroll
        for (int ni = 0; ni < 4; ++ni) ss += acc[mi][ni][r] * acc[mi][ni][r];
        #pragma unroll
        for (int off = 8; off > 0; off >>= 1) ss += __shfl_xor(ss, off);
        float inv = rsqrtf(ss * (1.0f / 64.0f) + EPS) * scale;
        int row = m_blk + wm + mi * 16 + g * 4 + r;
        #pragma unroll
        for (int ni = 0; ni < 4; ++ni)
          C[(long long)row * QKS + col_base + ni * 16 + c] = f2bf(acc[mi][ni][r] * inv * w[ni]);
      }
  } else if (col_base < 3072) {
    #pragma unroll
    for (int mi = 0; mi < 4; ++mi)
      #pragma unroll
      for (int r = 0; r < 4; ++r) {
        int row = m_blk + wm + mi * 16 + g * 4 + r;
        #pragma unroll
        for (int ni = 0; ni < 4; ++ni)
          C[(long long)row * QKS + col_base + ni * 16 + c] = f2bf(acc[mi][ni][r]);
      }
  } else if (col_base == 3072) {
    #pragma unroll
    for (int mi = 0; mi < 4; ++mi)
      #pragma unroll
      for (int r = 0; r < 4; ++r) {
        int row = m_blk + wm + mi * 16 + g * 4 + r;
        float v = acc[mi][0][r];
        gate[(long long)row * 16 + c] = 1.0f / (1.0f + __expf(-v));
      }
  }
}

// ---------- 3. generic tiled GEMM (o-proj): C=A@B^T (+res), dtype-dispatched ----------
__global__ void gemm_tiled(const ushort_t* __restrict__ A, const ushort_t* __restrict__ B,
                           void* __restrict__ Cv, const void* __restrict__ res,
                           const int* __restrict__ flag,
                           int K, int lda, int ldb, int ldc) {
  __shared__ ushort_t As[128 * 32];
  __shared__ ushort_t Bs[128 * 32];
  int tid = threadIdx.x, wave = tid >> 6, lane = tid & 63;
  int m_blk = blockIdx.y * 128, n_blk = blockIdx.x * 128;
  int wm = (wave & 1) * 64, wn = (wave >> 1) * 64;
  int g = lane >> 4, c = lane & 15;
  int arow = lane >> 2;
  int akc = (lane & 3) << 3;
  f32x4 acc[4][4] = {};
  for (int kt = 0; kt < K; kt += 32) {
    #pragma unroll
    for (int i = 0; i < 2; ++i) {
      int rbase = (i * 4 + wave) * 16;
      gll16(A + (long long)(m_blk + rbase + arow) * lda + kt + akc, &As[rbase * 32]);
      gll16(B + (long long)(n_blk + rbase + arow) * ldb + kt + akc, &Bs[rbase * 32]);
    }
    __syncthreads();
    bf16x8 af[4], bfr[4];
    #pragma unroll
    for (int mi = 0; mi < 4; ++mi)
      af[mi] = *(const bf16x8*)&As[(wm + mi * 16 + c) * 32 + (g << 3)];
    #pragma unroll
    for (int ni = 0; ni < 4; ++ni)
      bfr[ni] = *(const bf16x8*)&Bs[(wn + ni * 16 + c) * 32 + (g << 3)];
    #pragma unroll
    for (int mi = 0; mi < 4; ++mi)
      #pragma unroll
      for (int ni = 0; ni < 4; ++ni)
        acc[mi][ni] = __builtin_amdgcn_mfma_f32_16x16x32_bf16(af[mi], bfr[ni], acc[mi][ni], 0, 0, 0);
    __syncthreads();
  }
  int outbf = flag ? *flag : 1;
  #pragma unroll
  for (int mi = 0; mi < 4; ++mi)
    #pragma unroll
    for (int ni = 0; ni < 4; ++ni)
      #pragma unroll
      for (int r = 0; r < 4; ++r) {
        int row = m_blk + wm + mi * 16 + g * 4 + r;
        int col = n_blk + wn + ni * 16 + c;
        long long idx = (long long)row * ldc + col;
        float v = acc[mi][ni][r];
        if (res) v += outbf ? bf2f(((const ushort_t*)res)[idx]) : ((const float*)res)[idx];
        if (outbf) ((ushort_t*)Cv)[idx] = f2bf(v);
        else       ((float*)Cv)[idx] = v;
      }
}

// ---------- 4. V transpose (bf16): Vt[bh][d][s] = qkv2[b*S+s][2048+h*64+d] ----------
__global__ void vt_kernel(const ushort_t* __restrict__ qkv, ushort_t* __restrict__ Vt) {
  __shared__ ushort_t tile[64][65];
  int s0 = blockIdx.x * 64;
  int bh = blockIdx.y;
  int b = bh >> 4, h = bh & 15;
  const ushort_t* src = qkv + (long long)b * SEQ * QKS + 2048 + h * 64;
  int d = threadIdx.x & 63, srow = threadIdx.x >> 6;
  #pragma unroll
  for (int i = 0; i < 16; ++i) {
    int sl = i * 4 + srow;
    tile[sl][d] = src[(long long)(s0 + sl) * QKS + d];
  }
  __syncthreads();
  ushort_t* dst = Vt + (long long)bh * 64 * SEQ + s0;
  int sl2 = threadIdx.x & 63, drow = threadIdx.x >> 6;
  #pragma unroll
  for (int i = 0; i < 16; ++i) {
    int dd = i * 4 + drow;
    dst[(long long)dd * SEQ + sl2] = tile[sl2][dd];
  }
}

// ---------- 5. flash attention: gll16 staging with XOR swizzle via GLOBAL address ----------
// grid (SEQ/64, 32). Physical LDS slot (row, sc) holds global chunk sc^(row&7):
// realized by pointing each gll16 lane at the permuted source chunk. Fragment
// reads use r8's conflict-free pattern. Declared LDS = 24576 (gll16 staging is
// the only variant that reports exact size — r3/r4 evidence).
__global__ void flash_kernel(const ushort_t* __restrict__ qkv, const ushort_t* __restrict__ Vt,
                             const float* __restrict__ gate, ushort_t* __restrict__ ao) {
  __shared__ ushort_t Ks[64 * 64];
  __shared__ ushort_t Vs[64 * 64];
  __shared__ ushort_t Ps[4][16 * 64];
  int tid = threadIdx.x, wave = tid >> 6, lane = tid & 63;
  int g = lane >> 4, c = lane & 15;
  int q0 = blockIdx.x * 64;
  int bh = blockIdx.y, b = bh >> 4, h = bh & 15;
  const ushort_t* qbase = qkv + (long long)b * SEQ * QKS + h * 64;
  const ushort_t* kbase = qbase + 1024;
  const ushort_t* vtbase = Vt + (long long)bh * 64 * SEQ;
  // q A-fragment: m=c, k=8g+j (and +32)
  int qrow = q0 + wave * 16 + c;
  bf16x8 qa0 = *(const bf16x8*)(qbase + (long long)qrow * QKS + (g << 3));
  bf16x8 qa1 = *(const bf16x8*)(qbase + (long long)qrow * QKS + 32 + (g << 3));
  f32x4 accO[4] = {};
  float m_i[4] = {-1e30f, -1e30f, -1e30f, -1e30f};
  float l_i[4] = {0.f, 0.f, 0.f, 0.f};
  int srow = lane >> 3;           // 0..7 within this wave's 8-row stage chunk
  int schk = lane & 7;            // physical 16B chunk this lane fills
  for (int s0 = 0; s0 < SEQ; s0 += 64) {
    // async stage: lane (srow,schk) of chunk rb fetches global chunk schk^(row&7)
    #pragma unroll
    for (int t = 0; t < 2; ++t) {
      int rb = t * 32 + wave * 8;
      int row = rb + srow;
      int gch = (schk ^ (row & 7)) << 3;
      gll16(kbase + (long long)(s0 + row) * QKS + gch, &Ks[rb * 64]);
      gll16(vtbase + (long long)row * SEQ + s0 + gch, &Vs[rb * 64]);
    }
    __syncthreads();
    // S = q.k^T (C-layout): sacc[ni][r] = S[q=4g+r][s=16ni+c]
    f32x4 sacc[4] = {};
    #pragma unroll
    for (int ni = 0; ni < 4; ++ni) {
      int n = ni * 16 + c;
      bf16x8 kb0 = *(const bf16x8*)&Ks[n * 64 + ((g ^ (n & 7)) << 3)];
      bf16x8 kb1 = *(const bf16x8*)&Ks[n * 64 + (((4 + g) ^ (n & 7)) << 3)];
      sacc[ni] = __builtin_amdgcn_mfma_f32_16x16x32_bf16(qa0, kb0, sacc[ni], 0, 0, 0);
      sacc[ni] = __builtin_amdgcn_mfma_f32_16x16x32_bf16(qa1, kb1, sacc[ni], 0, 0, 0);
    }
    // per-row online softmax; 16-lane reduce (xor 8,4,2,1 stays in the g-group)
    float alpha[4];
    #pragma unroll
    for (int r = 0; r < 4; ++r) {
      float mx = fmaxf(fmaxf(sacc[0][r], sacc[1][r]), fmaxf(sacc[2][r], sacc[3][r]));
      #pragma unroll
      for (int off = 8; off > 0; off >>= 1) mx = fmaxf(mx, __shfl_xor(mx, off));
      float mn = fmaxf(m_i[r], mx);
      alpha[r] = __expf(m_i[r] - mn);
      m_i[r] = mn;
      int q = g * 4 + r;
      int sw = (q & 7) << 3;                // row swizzle mask (elements)
      float rs = 0.f;
      #pragma unroll
      for (int ni = 0; ni < 4; ++ni) {
        float p = __expf(sacc[ni][r] - mn);
        rs += p;
        int col = ni * 16 + c;
        Ps[wave][q * 64 + ((col & 56) ^ sw) + (col & 7)] = f2bf(p);
      }
      #pragma unroll
      for (int off = 8; off > 0; off >>= 1) rs += __shfl_xor(rs, off);
      l_i[r] = l_i[r] * alpha[r] + rs;
    }
    #pragma unroll
    for (int di = 0; di < 4; ++di)
      #pragma unroll
      for (int r = 0; r < 4; ++r) accO[di][r] *= alpha[r];
    // P A-fragment: row q=c, chunks g / 4+g (swizzled by c&7)
    bf16x8 pa0 = *(const bf16x8*)&Ps[wave][c * 64 + ((g ^ (c & 7)) << 3)];
    bf16x8 pa1 = *(const bf16x8*)&Ps[wave][c * 64 + (((4 + g) ^ (c & 7)) << 3)];
    // O += P.V : accO[di][r] = O[q=4g+r][d=16di+c]
    #pragma unroll
    for (int di = 0; di < 4; ++di) {
      int n = di * 16 + c;
      bf16x8 vb0 = *(const bf16x8*)&Vs[n * 64 + ((g ^ (n & 7)) << 3)];
      bf16x8 vb1 = *(const bf16x8*)&Vs[n * 64 + (((4 + g) ^ (n & 7)) << 3)];
      accO[di] = __builtin_amdgcn_mfma_f32_16x16x32_bf16(pa0, vb0, accO[di], 0, 0, 0);
      accO[di] = __builtin_amdgcn_mfma_f32_16x16x32_bf16(pa1, vb1, accO[di], 0, 0, 0);
    }
    __syncthreads();
  }
  // epilogue: O * sigmoid(gate) / l -> ao[b][q][h*64+d]
  #pragma unroll
  for (int r = 0; r < 4; ++r) {
    int row = q0 + wave * 16 + g * 4 + r;
    float sg = gate[(long long)(b * SEQ + row) * 16 + h];  // pre-sigmoided
    float scale = sg / l_i[r];
    #pragma unroll
    for (int di = 0; di < 4; ++di) {
      int col = h * 64 + di * 16 + c;
      ao[(long long)(b * SEQ + row) * 1024 + col] = f2bf(accO[di][r] * scale);
    }
  }
}

extern "C" void kernel_launch(void* const* d_in, const int* in_sizes, int n_in,
                              void* d_out, int out_size, void* d_ws, size_t ws_size,
                              hipStream_t stream) {
  (void)in_sizes; (void)n_in; (void)out_size; (void)ws_size;
  char* ws = (char*)d_ws;
  ushort_t* Wcat = (ushort_t*)(ws);                             // 7 MB: 3200x1024 bf16 (qkvw|gw|pad)
  ushort_t* ow   = (ushort_t*)(ws + (7ll << 20));               // 2 MB bf16 1024x1024
  float*    pwf  = (float*)   (ws + (9ll << 20));               // 4 KB
  float*    qnf  = (float*)   (ws + (9ll << 20) + (8 << 10));
  float*    knf  = (float*)   (ws + (9ll << 20) + (12 << 10));
  int*      flag = (int*)     (ws + (9ll << 20) + (16 << 10));
  float*    gate = (float*)   (ws + (9ll << 20) + (64 << 10));  // 256 KB fp32 (sigmoided)
  ushort_t* xn   = (ushort_t*)(ws + (10ll << 20));              // 8 MB bf16 4096x1024
  ushort_t* qkv2 = (ushort_t*)(ws + (18ll << 20));              // 26 MB bf16 4096x3200
  ushort_t* Vt   = (ushort_t*)(ws + (44ll << 20));              // 8 MB bf16 32x64x2048
  ushort_t* ao   = (ushort_t*)(ws + (52ll << 20));              // 8 MB bf16 4096x1024

  // 0. detect + canonicalize weights
  detect_kernel<<<1, 256, 0, stream>>>((const unsigned int*)d_in[0], flag);
  conv_f32<<<4, 256, 0, stream>>>(d_in[1], pwf, 1024, flag);
  conv_b16<<<12288, 256, 0, stream>>>(d_in[2], Wcat, 3145728, flag);          // qkv_w -> rows 0..3071
  conv_b16<<<64, 256, 0, stream>>>(d_in[3], Wcat + 3072 * 1024, 16384, flag); // gate_w -> rows 3072..3087
  conv_b16<<<4096, 256, 0, stream>>>(d_in[4], ow, 1048576, flag);
  conv_f32<<<1, 256, 0, stream>>>(d_in[5], qnf, 64, flag);
  conv_f32<<<1, 256, 0, stream>>>(d_in[6], knf, 64, flag);

  // 1. prenorm (raw x -> bf16 xn)
  prenorm_kernel<<<MROWS, 256, 0, stream>>>(d_in[0], pwf, xn, flag);
  // 2. fused qkv+gate GEMM with qk-norm / sigmoid epilogue (N=3200 incl. pad tile)
  gemm_qkv_fused<<<dim3(25, 32), 256, 0, stream>>>(xn, Wcat, qkv2, gate, qnf, knf);
  // 3. V transpose
  vt_kernel<<<dim3(32, 32), 256, 0, stream>>>(qkv2, Vt);
  // 4. flash attention (fused gate multiply)
  flash_kernel<<<dim3(32, 32), 256, 0, stream>>>(qkv2, Vt, gate, ao);
  // 5. out = ao @ o_w^T + x (raw residual), dtype-dispatched store
  gemm_tiled<<<dim3(8, 32), 256, 0, stream>>>(ao, ow, d_out, d_in[0], flag,
                                              1024, 1024, 1024, 1024);
}

// Round 10
// 240.183 us; speedup vs baseline: 1.5211x; 1.2359x over previous
//
#include <hip/hip_runtime.h>
#include <math.h>

typedef __bf16 bf16x8 __attribute__((ext_vector_type(8)));
typedef float f32x4 __attribute__((ext_vector_type(4)));
typedef unsigned short ushort_t;

#define SEQ 2048
#define MROWS 4096          // B*S
#define EPS 1e-5f
#define QKS 3200            // fused qkv output row stride (q 0..1023, k 1024.., v 2048.., gate 3072..3087, pad)
#define LOG2E 1.4426950408889634f
#define SMAX_B2 17.32f      // static softmax max in base-2 units (= 12 * log2e; |s|<=8.1 by Cauchy-Schwarz)

#if __has_builtin(__builtin_amdgcn_exp2f)
#define EXP2(x) __builtin_amdgcn_exp2f(x)
#else
#define EXP2(x) exp2f(x)
#endif

// ---------- bf16 helpers ----------
__device__ __forceinline__ float bf2f(ushort_t u) {
  union { unsigned int i; float f; } c; c.i = ((unsigned int)u) << 16; return c.f;
}
__device__ __forceinline__ ushort_t f2bf(float f) {           // manual RNE (cold paths)
  union { unsigned int i; float f; } c; c.f = f;
  unsigned int i = c.i;
  unsigned int r = i + 0x7fffu + ((i >> 16) & 1u);
  return (ushort_t)(r >> 16);
}
__device__ __forceinline__ ushort_t f2bf_fast(float f) {      // native v_cvt (flash hot path)
  union { __bf16 b; ushort_t u; } cv; cv.b = (__bf16)f; return cv.u;
}

// ---------- reductions ----------
__device__ __forceinline__ float wave_sum(float v) {
  #pragma unroll
  for (int off = 32; off > 0; off >>= 1) v += __shfl_xor(v, off);
  return v;
}

// ---------- 0a. dtype detector: is x bf16 (1) or fp32 (0)? ----------
__global__ void detect_kernel(const unsigned int* __restrict__ xraw, int* __restrict__ flag) {
  int tid = threadIdx.x;
  int cnt = 0;
  for (int i = tid; i < 4096; i += 256) {
    unsigned int e = (xraw[i] >> 7) & 0xFFu;
    cnt += (e >= 100u && e <= 150u) ? 1 : 0;
  }
  __shared__ int sred[256];
  sred[tid] = cnt;
  __syncthreads();
  for (int s = 128; s > 0; s >>= 1) {
    if (tid < s) sred[tid] += sred[tid + s];
    __syncthreads();
  }
  if (tid == 0) flag[0] = (sred[0] > 2048) ? 1 : 0;
}

// ---------- 0b. single merged weight-prep kernel (replaces 6 conv launches) ----------
__global__ void prep_kernel(const void* __restrict__ qkvw_in, const void* __restrict__ gw_in,
                            const void* __restrict__ ow_in, const void* __restrict__ pw_in,
                            const void* __restrict__ qn_in, const void* __restrict__ kn_in,
                            ushort_t* __restrict__ Wcat, ushort_t* __restrict__ ow,
                            float* __restrict__ pwf, float* __restrict__ qnf,
                            float* __restrict__ knf, const int* __restrict__ flag) {
  int bid = blockIdx.x, tid = threadIdx.x;
  int bf = *flag;
  if (bid < 12288) {                      // qkv_w -> Wcat rows 0..3071
    int i = bid * 256 + tid;
    Wcat[i] = bf ? ((const ushort_t*)qkvw_in)[i] : f2bf(((const float*)qkvw_in)[i]);
  } else if (bid < 12352) {               // gate_w -> Wcat rows 3072..3087
    int i = (bid - 12288) * 256 + tid;
    Wcat[3072 * 1024 + i] = bf ? ((const ushort_t*)gw_in)[i] : f2bf(((const float*)gw_in)[i]);
  } else if (bid < 16448) {               // o_w
    int i = (bid - 12352) * 256 + tid;
    ow[i] = bf ? ((const ushort_t*)ow_in)[i] : f2bf(((const float*)ow_in)[i]);
  } else {                                // prenorm_w (1024 f32) + q/k norm weights (64 each)
    for (int i = tid; i < 1024; i += 256)
      pwf[i] = bf ? bf2f(((const ushort_t*)pw_in)[i]) : ((const float*)pw_in)[i];
    if (tid < 64) {
      qnf[tid] = bf ? bf2f(((const ushort_t*)qn_in)[tid]) : ((const float*)qn_in)[tid];
      knf[tid] = bf ? bf2f(((const ushort_t*)kn_in)[tid]) : ((const float*)kn_in)[tid];
    }
  }
}

// ---------- 1. prenorm RMSNorm (raw x per flag -> bf16 xn) ----------
__global__ void prenorm_kernel(const void* __restrict__ xraw,
                               const float* __restrict__ w,
                               ushort_t* __restrict__ xn,
                               const int* __restrict__ flag) {
  int row = blockIdx.x;
  int tid = threadIdx.x;
  float4 u;
  if (*flag) {
    ushort4 s = ((const ushort4*)xraw)[row * 256 + tid];
    u.x = bf2f(s.x); u.y = bf2f(s.y); u.z = bf2f(s.z); u.w = bf2f(s.w);
  } else {
    u = ((const float4*)xraw)[row * 256 + tid];
  }
  float ss = u.x*u.x + u.y*u.y + u.z*u.z + u.w*u.w;
  ss = wave_sum(ss);
  __shared__ float red[4];
  if ((tid & 63) == 0) red[tid >> 6] = ss;
  __syncthreads();
  float total = red[0] + red[1] + red[2] + red[3];
  float inv = rsqrtf(total * (1.0f / 1024.0f) + EPS);
  float4 wu = ((const float4*)w)[tid];
  ushort4 o;
  o.x = f2bf(u.x * inv * wu.x);
  o.y = f2bf(u.y * inv * wu.y);
  o.z = f2bf(u.z * inv * wu.z);
  o.w = f2bf(u.w * inv * wu.w);
  ((ushort4*)(xn + (long long)row * 1024))[tid] = o;
}

// ---------- async global->LDS 16B ----------
__device__ __forceinline__ void gll16(const ushort_t* g, ushort_t* l) {
  __builtin_amdgcn_global_load_lds(
      (const __attribute__((address_space(1))) unsigned int*)g,
      (__attribute__((address_space(3))) unsigned int*)l, 16, 0, 0);
}

// ---------- 2. fused qkv+gate GEMM, 128x128 tile (m97 structure) ----------
// q gets 0.125*log2e folded in (flash softmax runs base-2, static max).
__global__ void gemm_qkv_fused(const ushort_t* __restrict__ A, const ushort_t* __restrict__ B,
                               ushort_t* __restrict__ C, float* __restrict__ gate,
                               const float* __restrict__ qw, const float* __restrict__ kw) {
  __shared__ ushort_t As[128 * 32];
  __shared__ ushort_t Bs[128 * 32];
  int tid = threadIdx.x, wave = tid >> 6, lane = tid & 63;
  int m_blk = blockIdx.y * 128, n_blk = blockIdx.x * 128;
  int wm = (wave & 1) * 64, wn = (wave >> 1) * 64;
  int g = lane >> 4, c = lane & 15;
  int arow = lane >> 2;
  int akc = (lane & 3) << 3;
  f32x4 acc[4][4] = {};
  for (int kt = 0; kt < 1024; kt += 32) {
    #pragma unroll
    for (int i = 0; i < 2; ++i) {
      int rbase = (i * 4 + wave) * 16;
      gll16(A + (long long)(m_blk + rbase + arow) * 1024 + kt + akc, &As[rbase * 32]);
      gll16(B + (long long)(n_blk + rbase + arow) * 1024 + kt + akc, &Bs[rbase * 32]);
    }
    __syncthreads();
    bf16x8 af[4], bfr[4];
    #pragma unroll
    for (int mi = 0; mi < 4; ++mi)
      af[mi] = *(const bf16x8*)&As[(wm + mi * 16 + c) * 32 + (g << 3)];
    #pragma unroll
    for (int ni = 0; ni < 4; ++ni)
      bfr[ni] = *(const bf16x8*)&Bs[(wn + ni * 16 + c) * 32 + (g << 3)];
    #pragma unroll
    for (int mi = 0; mi < 4; ++mi)
      #pragma unroll
      for (int ni = 0; ni < 4; ++ni)
        acc[mi][ni] = __builtin_amdgcn_mfma_f32_16x16x32_bf16(af[mi], bfr[ni], acc[mi][ni], 0, 0, 0);
    __syncthreads();
  }
  int col_base = n_blk + wn;   // 64-aligned; never straddles q/k/v/gate boundaries
  if (col_base < 2048) {
    int isk = col_base >= 1024;
    float scale = isk ? 1.0f : (0.125f * LOG2E);   // softmax scale + base-2 fold on q
    const float* nw = isk ? kw : qw;
    float w[4];
    #pragma unroll
    for (int ni = 0; ni < 4; ++ni) w[ni] = nw[ni * 16 + c];
    #pragma unroll
    for (int mi = 0; mi < 4; ++mi)
      #pragma unroll
      for (int r = 0; r < 4; ++r) {
        float ss = 0.f;
        #pragma unroll
        for (int ni = 0; ni < 4; ++ni) ss += acc[mi][ni][r] * acc[mi][ni][r];
        #pragma unroll
        for (int off = 8; off > 0; off >>= 1) ss += __shfl_xor(ss, off);
        float inv = rsqrtf(ss * (1.0f / 64.0f) + EPS) * scale;
        int row = m_blk + wm + mi * 16 + g * 4 + r;
        #pragma unroll
        for (int ni = 0; ni < 4; ++ni)
          C[(long long)row * QKS + col_base + ni * 16 + c] = f2bf(acc[mi][ni][r] * inv * w[ni]);
      }
  } else if (col_base < 3072) {
    #pragma unroll
    for (int mi = 0; mi < 4; ++mi)
      #pragma unroll
      for (int r = 0; r < 4; ++r) {
        int row = m_blk + wm + mi * 16 + g * 4 + r;
        #pragma unroll
        for (int ni = 0; ni < 4; ++ni)
          C[(long long)row * QKS + col_base + ni * 16 + c] = f2bf(acc[mi][ni][r]);
      }
  } else if (col_base == 3072) {
    #pragma unroll
    for (int mi = 0; mi < 4; ++mi)
      #pragma unroll
      for (int r = 0; r < 4; ++r) {
        int row = m_blk + wm + mi * 16 + g * 4 + r;
        float v = acc[mi][0][r];
        gate[(long long)row * 16 + c] = 1.0f / (1.0f + __expf(-v));
      }
  }
}

// ---------- 3. generic tiled GEMM (o-proj): C=A@B^T (+res), dtype-dispatched ----------
__global__ void gemm_tiled(const ushort_t* __restrict__ A, const ushort_t* __restrict__ B,
                           void* __restrict__ Cv, const void* __restrict__ res,
                           const int* __restrict__ flag,
                           int K, int lda, int ldb, int ldc) {
  __shared__ ushort_t As[128 * 32];
  __shared__ ushort_t Bs[128 * 32];
  int tid = threadIdx.x, wave = tid >> 6, lane = tid & 63;
  int m_blk = blockIdx.y * 128, n_blk = blockIdx.x * 128;
  int wm = (wave & 1) * 64, wn = (wave >> 1) * 64;
  int g = lane >> 4, c = lane & 15;
  int arow = lane >> 2;
  int akc = (lane & 3) << 3;
  f32x4 acc[4][4] = {};
  for (int kt = 0; kt < K; kt += 32) {
    #pragma unroll
    for (int i = 0; i < 2; ++i) {
      int rbase = (i * 4 + wave) * 16;
      gll16(A + (long long)(m_blk + rbase + arow) * lda + kt + akc, &As[rbase * 32]);
      gll16(B + (long long)(n_blk + rbase + arow) * ldb + kt + akc, &Bs[rbase * 32]);
    }
    __syncthreads();
    bf16x8 af[4], bfr[4];
    #pragma unroll
    for (int mi = 0; mi < 4; ++mi)
      af[mi] = *(const bf16x8*)&As[(wm + mi * 16 + c) * 32 + (g << 3)];
    #pragma unroll
    for (int ni = 0; ni < 4; ++ni)
      bfr[ni] = *(const bf16x8*)&Bs[(wn + ni * 16 + c) * 32 + (g << 3)];
    #pragma unroll
    for (int mi = 0; mi < 4; ++mi)
      #pragma unroll
      for (int ni = 0; ni < 4; ++ni)
        acc[mi][ni] = __builtin_amdgcn_mfma_f32_16x16x32_bf16(af[mi], bfr[ni], acc[mi][ni], 0, 0, 0);
    __syncthreads();
  }
  int outbf = flag ? *flag : 1;
  #pragma unroll
  for (int mi = 0; mi < 4; ++mi)
    #pragma unroll
    for (int ni = 0; ni < 4; ++ni)
      #pragma unroll
      for (int r = 0; r < 4; ++r) {
        int row = m_blk + wm + mi * 16 + g * 4 + r;
        int col = n_blk + wn + ni * 16 + c;
        long long idx = (long long)row * ldc + col;
        float v = acc[mi][ni][r];
        if (res) v += outbf ? bf2f(((const ushort_t*)res)[idx]) : ((const float*)res)[idx];
        if (outbf) ((ushort_t*)Cv)[idx] = f2bf(v);
        else       ((float*)Cv)[idx] = v;
      }
}

// ---------- 4. V transpose (bf16): Vt[bh][d][s] = qkv2[b*S+s][2048+h*64+d] ----------
__global__ void vt_kernel(const ushort_t* __restrict__ qkv, ushort_t* __restrict__ Vt) {
  __shared__ ushort_t tile[64][65];
  int s0 = blockIdx.x * 64;
  int bh = blockIdx.y;
  int b = bh >> 4, h = bh & 15;
  const ushort_t* src = qkv + (long long)b * SEQ * QKS + 2048 + h * 64;
  int d = threadIdx.x & 63, srow = threadIdx.x >> 6;
  #pragma unroll
  for (int i = 0; i < 16; ++i) {
    int sl = i * 4 + srow;
    tile[sl][d] = src[(long long)(s0 + sl) * QKS + d];
  }
  __syncthreads();
  ushort_t* dst = Vt + (long long)bh * 64 * SEQ + s0;
  int sl2 = threadIdx.x & 63, drow = threadIdx.x >> 6;
  #pragma unroll
  for (int i = 0; i < 16; ++i) {
    int dd = i * 4 + drow;
    dst[(long long)dd * SEQ + sl2] = tile[sl2][dd];
  }
}

// ---------- 5. flash attention: gll16+global-XOR staging, STATIC-MAX base-2 softmax ----------
// grid (SEQ/64, 32). No online max (|scores|<=8.1 by Cauchy-Schwarz after RMSNorm;
// static M=12 in base-2 units). l reduced once in epilogue from per-lane partials.
__global__ void flash_kernel(const ushort_t* __restrict__ qkv, const ushort_t* __restrict__ Vt,
                             const float* __restrict__ gate, ushort_t* __restrict__ ao) {
  __shared__ ushort_t Ks[64 * 64];
  __shared__ ushort_t Vs[64 * 64];
  __shared__ ushort_t Ps[4][16 * 64];
  int tid = threadIdx.x, wave = tid >> 6, lane = tid & 63;
  int g = lane >> 4, c = lane & 15;
  int q0 = blockIdx.x * 64;
  int bh = blockIdx.y, b = bh >> 4, h = bh & 15;
  const ushort_t* qbase = qkv + (long long)b * SEQ * QKS + h * 64;
  const ushort_t* kbase = qbase + 1024;
  const ushort_t* vtbase = Vt + (long long)bh * 64 * SEQ;
  // q A-fragment: m=c, k=8g+j (and +32)
  int qrow = q0 + wave * 16 + c;
  bf16x8 qa0 = *(const bf16x8*)(qbase + (long long)qrow * QKS + (g << 3));
  bf16x8 qa1 = *(const bf16x8*)(qbase + (long long)qrow * QKS + 32 + (g << 3));
  f32x4 accO[4] = {};
  float l_p[4] = {0.f, 0.f, 0.f, 0.f};   // per-lane l partials (rows 4g+r, this lane's 4 cols)
  int srow = lane >> 3;           // 0..7 within this wave's 8-row stage chunk
  int schk = lane & 7;            // physical 16B chunk this lane fills
  for (int s0 = 0; s0 < SEQ; s0 += 64) {
    // async stage: physical slot (row, schk) holds global chunk schk^(row&7)
    #pragma unroll
    for (int t = 0; t < 2; ++t) {
      int rb = t * 32 + wave * 8;
      int row = rb + srow;
      int gch = (schk ^ (row & 7)) << 3;
      gll16(kbase + (long long)(s0 + row) * QKS + gch, &Ks[rb * 64]);
      gll16(vtbase + (long long)row * SEQ + s0 + gch, &Vs[rb * 64]);
    }
    __syncthreads();
    // S = q.k^T (C-layout): sacc[ni][r] = S[q=4g+r][s=16ni+c]  (base-2 units)
    f32x4 sacc[4] = {};
    #pragma unroll
    for (int ni = 0; ni < 4; ++ni) {
      int n = ni * 16 + c;
      bf16x8 kb0 = *(const bf16x8*)&Ks[n * 64 + ((g ^ (n & 7)) << 3)];
      bf16x8 kb1 = *(const bf16x8*)&Ks[n * 64 + (((4 + g) ^ (n & 7)) << 3)];
      sacc[ni] = __builtin_amdgcn_mfma_f32_16x16x32_bf16(qa0, kb0, sacc[ni], 0, 0, 0);
      sacc[ni] = __builtin_amdgcn_mfma_f32_16x16x32_bf16(qa1, kb1, sacc[ni], 0, 0, 0);
    }
    // static-max softmax: p = 2^(s - M); accumulate per-lane l partials
    #pragma unroll
    for (int r = 0; r < 4; ++r) {
      int q = g * 4 + r;
      int sw = (q & 7) << 3;                // row swizzle mask (elements)
      #pragma unroll
      for (int ni = 0; ni < 4; ++ni) {
        float p = EXP2(sacc[ni][r] - SMAX_B2);
        l_p[r] += p;
        int col = ni * 16 + c;
        Ps[wave][q * 64 + ((col & 56) ^ sw) + (col & 7)] = f2bf_fast(p);
      }
    }
    // P A-fragment: row q=c, chunks g / 4+g (swizzled by c&7)
    bf16x8 pa0 = *(const bf16x8*)&Ps[wave][c * 64 + ((g ^ (c & 7)) << 3)];
    bf16x8 pa1 = *(const bf16x8*)&Ps[wave][c * 64 + (((4 + g) ^ (c & 7)) << 3)];
    // O += P.V : accO[di][r] = O[q=4g+r][d=16di+c]
    #pragma unroll
    for (int di = 0; di < 4; ++di) {
      int n = di * 16 + c;
      bf16x8 vb0 = *(const bf16x8*)&Vs[n * 64 + ((g ^ (n & 7)) << 3)];
      bf16x8 vb1 = *(const bf16x8*)&Vs[n * 64 + (((4 + g) ^ (n & 7)) << 3)];
      accO[di] = __builtin_amdgcn_mfma_f32_16x16x32_bf16(pa0, vb0, accO[di], 0, 0, 0);
      accO[di] = __builtin_amdgcn_mfma_f32_16x16x32_bf16(pa1, vb1, accO[di], 0, 0, 0);
    }
    __syncthreads();
  }
  // epilogue: reduce l over the 16-lane c-group, then O * sigmoid(gate) / l
  #pragma unroll
  for (int r = 0; r < 4; ++r) {
    #pragma unroll
    for (int off = 8; off > 0; off >>= 1) l_p[r] += __shfl_xor(l_p[r], off);
    int row = q0 + wave * 16 + g * 4 + r;
    float sg = gate[(long long)(b * SEQ + row) * 16 + h];  // pre-sigmoided
    float scale = sg / l_p[r];
    #pragma unroll
    for (int di = 0; di < 4; ++di) {
      int col = h * 64 + di * 16 + c;
      ao[(long long)(b * SEQ + row) * 1024 + col] = f2bf_fast(accO[di][r] * scale);
    }
  }
}

extern "C" void kernel_launch(void* const* d_in, const int* in_sizes, int n_in,
                              void* d_out, int out_size, void* d_ws, size_t ws_size,
                              hipStream_t stream) {
  (void)in_sizes; (void)n_in; (void)out_size; (void)ws_size;
  char* ws = (char*)d_ws;
  ushort_t* Wcat = (ushort_t*)(ws);                             // 7 MB: 3200x1024 bf16 (qkvw|gw|pad)
  ushort_t* ow   = (ushort_t*)(ws + (7ll << 20));               // 2 MB bf16 1024x1024
  float*    pwf  = (float*)   (ws + (9ll << 20));               // 4 KB
  float*    qnf  = (float*)   (ws + (9ll << 20) + (8 << 10));
  float*    knf  = (float*)   (ws + (9ll << 20) + (12 << 10));
  int*      flag = (int*)     (ws + (9ll << 20) + (16 << 10));
  float*    gate = (float*)   (ws + (9ll << 20) + (64 << 10));  // 256 KB fp32 (sigmoided)
  ushort_t* xn   = (ushort_t*)(ws + (10ll << 20));              // 8 MB bf16 4096x1024
  ushort_t* qkv2 = (ushort_t*)(ws + (18ll << 20));              // 26 MB bf16 4096x3200
  ushort_t* Vt   = (ushort_t*)(ws + (44ll << 20));              // 8 MB bf16 32x64x2048
  ushort_t* ao   = (ushort_t*)(ws + (52ll << 20));              // 8 MB bf16 4096x1024

  // 0. detect + merged weight prep
  detect_kernel<<<1, 256, 0, stream>>>((const unsigned int*)d_in[0], flag);
  prep_kernel<<<16449, 256, 0, stream>>>(d_in[2], d_in[3], d_in[4], d_in[1], d_in[5], d_in[6],
                                         Wcat, ow, pwf, qnf, knf, flag);
  // 1. prenorm (raw x -> bf16 xn)
  prenorm_kernel<<<MROWS, 256, 0, stream>>>(d_in[0], pwf, xn, flag);
  // 2. fused qkv+gate GEMM with qk-norm / sigmoid epilogue (N=3200 incl. pad tile)
  gemm_qkv_fused<<<dim3(25, 32), 256, 0, stream>>>(xn, Wcat, qkv2, gate, qnf, knf);
  // 3. V transpose
  vt_kernel<<<dim3(32, 32), 256, 0, stream>>>(qkv2, Vt);
  // 4. flash attention (fused gate multiply)
  flash_kernel<<<dim3(32, 32), 256, 0, stream>>>(qkv2, Vt, gate, ao);
  // 5. out = ao @ o_w^T + x (raw residual), dtype-dispatched store
  gemm_tiled<<<dim3(8, 32), 256, 0, stream>>>(ao, ow, d_out, d_in[0], flag,
                                              1024, 1024, 1024, 1024);
}